// Round 4
// baseline (296.224 us; speedup 1.0000x reference)
//
#include <hip/hip_runtime.h>

// EMA along T for x[B=8, T=4096, F=1024] fp32.
// y_t = a*y_{t-1} + (1-a)*x_t, a=0.9, y_{-1}=0.
//
// Chunked scan with truncated warm-up (0.9^64 ~ 1.2e-3; measured absmax
// 3.9e-3 vs threshold 2.58e-2).
//
// R3 -> R4: fix OOB crash — with L=16 < W=64, chunks 1..3 had ts = t0-W < 0.
// Now ts = max(t0-W, 0); span stays %4==0 (80 or t0+16), and chunks 1..3
// become exact (full-prefix warm-up).
//
// Structure (from R3):
//  - Per-wave CONTIGUOUS streams: one wave covers all of F (lane loads f4
//    slots lane+64j, j=0..3 -> 4 KiB contiguous per t), successive t-steps
//    adjacent -> each wave reads/writes one unbroken region. R2's
//    4KiB-strided 1KiB windows thrashed DRAM rows (~1.4 TB/s read).
//  - L=16 -> 256 chunks -> 2048 waves (8/CU). Warm-up re-reads L3-served.
//  - 4-deep software pipeline: 16 loads (16 KiB) in flight per wave.

using f4 = __attribute__((ext_vector_type(4))) float;

constexpr int Bn = 8;
constexpr int Tn = 4096;
constexpr int F4 = 256;        // 1024 floats / 4
constexpr int L  = 16;         // outputs per wave-chunk -> 256 chunks
constexpr int W  = 64;         // warm-up steps (0.9^64 ~ 1.18e-3)
constexpr float A   = 0.9f;
constexpr float OMA = 0.1f;    // 1 - alpha

__global__ __launch_bounds__(256) void ema_kernel(const f4* __restrict__ x,
                                                  f4* __restrict__ y) {
    const int lane  = threadIdx.x & 63;
    const int wave  = threadIdx.x >> 6;          // 0..3
    const int blk   = blockIdx.x;                // 0..511
    const int b     = blk >> 6;                  // 0..7
    const int chunk = ((blk & 63) << 2) | wave;  // 0..255
    const int t0    = chunk * L;

    const size_t base = (size_t)b * Tn * F4 + lane;
    const f4* __restrict__ xp = x + base;
    f4*       __restrict__ yp = y + base;

    float acc[16];
    #pragma unroll
    for (int i = 0; i < 16; ++i) acc[i] = 0.f;

    int ts = t0 - W;                             // wave-uniform
    if (ts < 0) ts = 0;
    const int te = t0 + L;

    auto LD = [&](f4* v, int t) {
        const f4* __restrict__ p = xp + (size_t)t * F4;
        #pragma unroll
        for (int j = 0; j < 4; ++j) v[j] = p[j * 64];
    };
    auto STEP = [&](const f4* v, int t) {
        #pragma unroll
        for (int j = 0; j < 4; ++j) {
            acc[4*j+0] = fmaf(A, acc[4*j+0], OMA * v[j].x);
            acc[4*j+1] = fmaf(A, acc[4*j+1], OMA * v[j].y);
            acc[4*j+2] = fmaf(A, acc[4*j+2], OMA * v[j].z);
            acc[4*j+3] = fmaf(A, acc[4*j+3], OMA * v[j].w);
        }
        if (t >= t0) {                           // wave-uniform
            f4* __restrict__ p = yp + (size_t)t * F4;
            #pragma unroll
            for (int j = 0; j < 4; ++j) {
                f4 o;
                o.x = acc[4*j+0]; o.y = acc[4*j+1];
                o.z = acc[4*j+2]; o.w = acc[4*j+3];
                __builtin_nontemporal_store(o, p + j * 64);
            }
        }
    };

    // 4-deep software pipeline over t in [ts, te); span is 80 or t0+16,
    // always a multiple of 4.
    f4 v0[4], v1[4], v2[4], v3[4];
    LD(v0, ts); LD(v1, ts + 1); LD(v2, ts + 2); LD(v3, ts + 3);
    for (int t = ts; t < te; t += 4) {
        STEP(v0, t);
        if (t + 4 < te) LD(v0, t + 4);
        STEP(v1, t + 1);
        if (t + 5 < te) LD(v1, t + 5);
        STEP(v2, t + 2);
        if (t + 6 < te) LD(v2, t + 6);
        STEP(v3, t + 3);
        if (t + 7 < te) LD(v3, t + 7);
    }
}

extern "C" void kernel_launch(void* const* d_in, const int* in_sizes, int n_in,
                              void* d_out, int out_size, void* d_ws, size_t ws_size,
                              hipStream_t stream) {
    const f4* x = (const f4*)d_in[0];
    f4*       y = (f4*)d_out;
    dim3 grid(Bn * 64);      // 512 blocks x 256 thr = 2048 waves, 8/CU
    dim3 block(256);
    ema_kernel<<<grid, block, 0, stream>>>(x, y);
}